// Round 16
// baseline (515.966 us; speedup 1.0000x reference)
//
#include <hip/hip_runtime.h>
#include <cstdint>

#define T_STEPS 200
#define B_TOTAL 8192
#define F_IN    40
#define H_DIM   128
#define C_OUT   5
#define ROWB    (T_STEPS * F_IN * 4)      // 32000 bytes per b row

typedef int si4 __attribute__((ext_vector_type(4)));

// scalar load: 4 dwords of x (wave-uniform address) -> 4 SGPRs
#define SLOAD4(dst, base, off)                                                 \
    asm volatile("s_load_dwordx4 %0, %1, %c2"                                  \
                 : "=s"(dst) : "s"(base), "i"(off))

#define ISSUE_ROW(BUF, xt)                                                     \
    SLOAD4(BUF[0], xt, 0);   SLOAD4(BUF[1], xt, 16);                           \
    SLOAD4(BUF[2], xt, 32);  SLOAD4(BUF[3], xt, 48);                           \
    SLOAD4(BUF[4], xt, 64);  SLOAD4(BUF[5], xt, 80);                           \
    SLOAD4(BUF[6], xt, 96);  SLOAD4(BUF[7], xt, 112);                          \
    SLOAD4(BUF[8], xt, 128); SLOAD4(BUF[9], xt, 144)

#define WAIT_LGKM0()                                                           \
    do {                                                                       \
        asm volatile("s_waitcnt lgkmcnt(0)" ::: "memory");                     \
        __builtin_amdgcn_sched_barrier(0);                                     \
    } while (0)

// ---------------------------------------------------------------------------
// Kernel A: layer-1 recurrence. Exact fp32 numerics (validated r2/r5-r15):
// per-step sequential-f FMA chain (f = 0..39), +b1, then ((0.9*m)+cur)-reset,
// each op individually rounded. 2 waves per b; lane li owns ONE h = w*64+li
// (40 weight VGPRs). x rows are wave-uniform -> loaded into SGPRs via
// s_load_dwordx4 (double-buffered A/B, prefetch t+1 under step t's FMAs);
// v_fma with SGPR src0 costs no VGPRs and no LDS. No LDS, no barriers ->
// occupancy limited only by VGPRs (~56). Plain-C FMAs (no volatile-asm ring:
// r14/r15 showed those poison register allocation -> scratch spills).
// ---------------------------------------------------------------------------
__global__ __launch_bounds__(256)
void snn_l1(const float* __restrict__ x,
            const float* __restrict__ w1,
            const float* __restrict__ b1,
            unsigned long long* __restrict__ masks)
{
    const int li = threadIdx.x & 63;
    const int wv = threadIdx.x >> 6;
    const int w  = wv & 1;                      // h-half: 0 -> h<64, 1 -> h>=64
    const int b  = blockIdx.x * 2 + (wv >> 1);  // grid 4096 -> b in [0,8192)
    const int h  = w * 64 + li;

    // one h row of w1: 40 VGPRs
    float wreg[F_IN];
    {
        const float4* wr = (const float4*)(w1 + h * F_IN);
#pragma unroll
        for (int q = 0; q < 10; ++q) {
            float4 t = wr[q];
            wreg[4*q+0] = t.x; wreg[4*q+1] = t.y;
            wreg[4*q+2] = t.z; wreg[4*q+3] = t.w;
        }
    }
    const float b1h = b1[h];
    float m = 0.0f, r = 0.0f;

    // wave-uniform x-row base and mask offset (forced scalar)
    const int xo = __builtin_amdgcn_readfirstlane(b * ROWB);
    const char* xbase = (const char*)x + xo;
    unsigned long long* mp = masks + __builtin_amdgcn_readfirstlane(b * 2 + w);

    si4 A[10], B[10];                           // x rows in SGPRs (2 x 40)

    ISSUE_ROW(A, xbase);                        // t = 0

    for (int t = 0; t < T_STEPS; t += 2) {
        // ---- step t (buffer A); prefetch t+1 into B ----
        WAIT_LGKM0();                           // A ready
        {
            const char* xt = xbase + (t + 1) * (F_IN * 4);   // t+1 <= 199
            ISSUE_ROW(B, xt);
        }
        {
            float acc = 0.0f;
#pragma unroll
            for (int k = 0; k < 10; ++k) {
                acc = __fmaf_rn(__int_as_float(A[k][0]), wreg[4*k+0], acc);
                acc = __fmaf_rn(__int_as_float(A[k][1]), wreg[4*k+1], acc);
                acc = __fmaf_rn(__int_as_float(A[k][2]), wreg[4*k+2], acc);
                acc = __fmaf_rn(__int_as_float(A[k][3]), wreg[4*k+3], acc);
            }
            m = __fsub_rn(__fadd_rn(__fmul_rn(0.9f, m), __fadd_rn(acc, b1h)), r);
            bool s0 = m > 1.0f;                 // == (m-1 > 0) exactly
            r = s0 ? 1.0f : 0.0f;
            unsigned long long bal = __ballot(s0);
            if (li == 0) *mp = bal;             // 8B half of masks[t][b]
            mp += B_TOTAL * 2;
        }
        // ---- step t+1 (buffer B); prefetch t+2 into A ----
        WAIT_LGKM0();                           // B ready
        if (t + 2 < T_STEPS) {
            const char* xt = xbase + (t + 2) * (F_IN * 4);
            ISSUE_ROW(A, xt);
        }
        {
            float acc = 0.0f;
#pragma unroll
            for (int k = 0; k < 10; ++k) {
                acc = __fmaf_rn(__int_as_float(B[k][0]), wreg[4*k+0], acc);
                acc = __fmaf_rn(__int_as_float(B[k][1]), wreg[4*k+1], acc);
                acc = __fmaf_rn(__int_as_float(B[k][2]), wreg[4*k+2], acc);
                acc = __fmaf_rn(__int_as_float(B[k][3]), wreg[4*k+3], acc);
            }
            m = __fsub_rn(__fadd_rn(__fmul_rn(0.9f, m), __fadd_rn(acc, b1h)), r);
            bool s0 = m > 1.0f;
            r = s0 ? 1.0f : 0.0f;
            unsigned long long bal = __ballot(s0);
            if (li == 0) *mp = bal;
            mp += B_TOTAL * 2;
        }
    }
}

// ---------------------------------------------------------------------------
// Kernel B: cur2 sums, parallel over (t,b). Ascending-h individually-rounded
// adds of w2[c][h] over spiking h — identical numerics to the validated l2.
// ---------------------------------------------------------------------------
__global__ __launch_bounds__(256)
void snn_l2a(const ulonglong2* __restrict__ masks,
             const float* __restrict__ w2,
             float* __restrict__ cur2)
{
    __shared__ float w2s[H_DIM * C_OUT];   // [h][c] for bank spread
    const int tid = threadIdx.x;
    for (int i = tid; i < H_DIM * C_OUT; i += 256) {
        const int c = i / H_DIM, h = i % H_DIM;
        w2s[h * C_OUT + c] = w2[i];
    }
    __syncthreads();

    const size_t gid = (size_t)blockIdx.x * 256 + tid;   // == t*B_TOTAL + b
    const ulonglong2 mk = masks[gid];
    float s0 = 0.f, s1 = 0.f, s2 = 0.f, s3 = 0.f, s4 = 0.f;

    auto acc32 = [&](uint32_t w, int base) {
        while (w) {
            const int h = base + __builtin_ctz(w);
            w &= w - 1;
            const float* wp = &w2s[h * C_OUT];
            s0 = __fadd_rn(s0, wp[0]);
            s1 = __fadd_rn(s1, wp[1]);
            s2 = __fadd_rn(s2, wp[2]);
            s3 = __fadd_rn(s3, wp[3]);
            s4 = __fadd_rn(s4, wp[4]);
        }
    };
    acc32((uint32_t)(mk.x & 0xffffffffull), 0);
    acc32((uint32_t)(mk.x >> 32), 32);
    acc32((uint32_t)(mk.y & 0xffffffffull), 64);
    acc32((uint32_t)(mk.y >> 32), 96);

    float* o = cur2 + gid * C_OUT;
    o[0] = s0; o[1] = s1; o[2] = s2; o[3] = s3; o[4] = s4;
}

// ---------------------------------------------------------------------------
// Kernel C: layer-2 recurrence over t. Lane = (b,c), coalesced cur2/out,
// depth-4 static-unrolled prefetch. Ops identical to validated l2.
// ---------------------------------------------------------------------------
__global__ __launch_bounds__(256)
void snn_l2b(const float* __restrict__ cur2,
             const float* __restrict__ b2,
             float* __restrict__ out)
{
    const int gid = blockIdx.x * 256 + threadIdx.x;      // b*5 + c
    const float b2c = b2[gid % 5];
    const int STRIDE = B_TOTAL * C_OUT;                  // 40960
    float m2 = 0.0f, r2 = 0.0f;

    float f0 = cur2[0 * (size_t)STRIDE + gid];
    float f1 = cur2[1 * (size_t)STRIDE + gid];
    float f2 = cur2[2 * (size_t)STRIDE + gid];
    float f3 = cur2[3 * (size_t)STRIDE + gid];

#define L2B_STEP(F, TT)                                                        \
    {                                                                          \
        const float cur = __fadd_rn(F, b2c);                                   \
        m2 = __fsub_rn(__fadd_rn(__fmul_rn(0.9f, m2), cur), r2);               \
        const float s = (m2 > 1.0f) ? 1.0f : 0.0f;                             \
        r2 = s;                                                                \
        out[(size_t)(TT) * STRIDE + gid] = s;                                  \
        F = ((TT) + 4 < T_STEPS) ? cur2[(size_t)((TT) + 4) * STRIDE + gid]     \
                                 : 0.0f;                                       \
    }

    for (int t = 0; t < T_STEPS; t += 4) {
        L2B_STEP(f0, t + 0)
        L2B_STEP(f1, t + 1)
        L2B_STEP(f2, t + 2)
        L2B_STEP(f3, t + 3)
    }
#undef L2B_STEP
}

extern "C" void kernel_launch(void* const* d_in, const int* in_sizes, int n_in,
                              void* d_out, int out_size, void* d_ws, size_t ws_size,
                              hipStream_t stream) {
    const float* x  = (const float*)d_in[0];
    const float* w1 = (const float*)d_in[1];
    const float* b1 = (const float*)d_in[2];
    const float* w2 = (const float*)d_in[3];
    const float* b2 = (const float*)d_in[4];
    float* out = (float*)d_out;

    // ws layout: masks [t][b] 16B each = 26,214,400 B; cur2 [t][b][c] fp32 =
    // 32,768,000 B; total ~59 MB.
    unsigned long long* masks = (unsigned long long*)d_ws;
    float* cur2 = (float*)((char*)d_ws + (size_t)T_STEPS * B_TOTAL * 16);

    snn_l1 <<<dim3(B_TOTAL / 2),             dim3(256), 0, stream>>>(x, w1, b1, masks);
    snn_l2a<<<dim3(T_STEPS * B_TOTAL / 256), dim3(256), 0, stream>>>((const ulonglong2*)masks, w2, cur2);
    snn_l2b<<<dim3(B_TOTAL * C_OUT / 256),   dim3(256), 0, stream>>>(cur2, b2, out);
}

// Round 17
// 294.176 us; speedup vs baseline: 1.7539x; 1.7539x over previous
//
#include <hip/hip_runtime.h>
#include <cstdint>

#define T_STEPS 200
#define B_TOTAL 8192
#define F_IN    40
#define H_DIM   128
#define C_OUT   5

#define CH      8                         // time steps per staged chunk
#define NCHUNK  (T_STEPS / CH)            // 25
#define CHB     (CH * F_IN * 4)           // 1280 bytes per chunk per b
#define WIN     2048                      // staged window bytes per b
#define ROWB    (T_STEPS * F_IN * 4)      // 32000 bytes per b

typedef float v2f __attribute__((ext_vector_type(2)));
typedef float v4f __attribute__((ext_vector_type(4)));

// v_pk_fma_f32: per-word IEEE fp32 FMA (bit-identical to v_fma_f32).
// op_sel broadcasts one word of the x-pair to both result words:
// LO -> word0 (x_f), HI -> word1 (x_{f+1}).  Validated bit-exact r6/r7.
#define PKFMA_LO(acc, xp, wp)                                                  \
    asm("v_pk_fma_f32 %0, %1, %2, %0 op_sel:[0,0,0] op_sel_hi:[0,1,1]"        \
        : "+v"(acc) : "v"(xp), "v"(wp))
#define PKFMA_HI(acc, xp, wp)                                                  \
    asm("v_pk_fma_f32 %0, %1, %2, %0 op_sel:[1,0,0] op_sel_hi:[1,1,1]"        \
        : "+v"(acc) : "v"(xp), "v"(wp))

// async global->LDS, 16B per lane, dest = wave-uniform base + lane*16
__device__ __forceinline__ void gload_lds16(const void* g, void* l) {
    __builtin_amdgcn_global_load_lds(
        (const __attribute__((address_space(1))) void*)g,
        (__attribute__((address_space(3))) void*)l, 16, 0, 0);
}

// ---------------------------------------------------------------------------
// Kernel A: layer-1 recurrence, NB=2 batch elements per wave.
// Exact fp32 numerics (validated r2/r5-r16): per-step sequential-f FMA chain
// (f = 0..39), +b1, then ((0.9*m)+cur)-reset, each op individually rounded.
// Structure = round-7 PASS (fastest to date, 255us) with the inner loop
// doubled: lane li owns h=li (acc.x) and h=li+64 (acc.y) for BOTH b0 and b1.
// Rationale: the compiler reloads the 40 weight pairs from cache every step
// no matter what (8 failed residency attempts, r6-r16); that ~60-inst cost is
// per-STEP, so doubling the per-step FMA work halves its relative cost.
// x staged 8 steps deep in per-wave-private LDS windows (2 KB per b), no
// barriers, vmcnt-counted double buffering.
// ---------------------------------------------------------------------------
__global__ __launch_bounds__(256, 4)
void snn_l1(const float* __restrict__ x,
            const float* __restrict__ w1,
            const float* __restrict__ b1,
            ulonglong2* __restrict__ masks)
{
    __shared__ __align__(16) char xs[2][4][2][WIN];   // [buf][wave][b][2KB] = 32 KiB

    const int li = threadIdx.x & 63;
    const int wv = threadIdx.x >> 6;
    const int b0 = blockIdx.x * 8 + wv * 2;     // grid 1024 -> b0 even, b1=b0+1
    const int hA = li, hB = li + 64;

    // weight pairs (wA_f, wB_f): shared by both b's
    v2f wab[F_IN];
    {
        const float* wArow = w1 + hA * F_IN;
        const float* wBrow = w1 + hB * F_IN;
#pragma unroll
        for (int f = 0; f < F_IN; ++f) {
            v2f p; p.x = wArow[f]; p.y = wBrow[f];
            wab[f] = p;
        }
    }
    const float b1A = b1[hA], b1B = b1[hB];
    float mA0 = 0.f, mB0 = 0.f, rA0 = 0.f, rB0 = 0.f;   // state for b0
    float mA1 = 0.f, mB1 = 0.f, rA1 = 0.f, rB1 = 0.f;   // state for b1

    // per-lane global src for each b row
    const char* xb0 = (const char*)x + (size_t)b0 * ROWB + (size_t)li * 16;
    const char* xb1 = xb0 + ROWB;

    auto winstart = [](int c) { return (c == NCHUNK - 1) ? (ROWB - WIN) : c * CHB; };

    // stage chunk 0 into buffer 0 (both b's)
    gload_lds16(xb0 + winstart(0),        &xs[0][wv][0][0]);
    gload_lds16(xb0 + winstart(0) + 1024, &xs[0][wv][0][1024]);
    gload_lds16(xb1 + winstart(0),        &xs[0][wv][1][0]);
    gload_lds16(xb1 + winstart(0) + 1024, &xs[0][wv][1][1024]);
    asm volatile("s_waitcnt vmcnt(0)" ::: "memory");

    ulonglong2* mp = masks + b0;                // store ptr, advance per t

    for (int c = 0; c < NCHUNK; ++c) {
        // prefetch next chunk into the other buffer (issue early, wait late)
        if (c + 1 < NCHUNK) {
            const int ws = winstart(c + 1);
            gload_lds16(xb0 + ws,        &xs[(c + 1) & 1][wv][0][0]);
            gload_lds16(xb0 + ws + 1024, &xs[(c + 1) & 1][wv][0][1024]);
            gload_lds16(xb1 + ws,        &xs[(c + 1) & 1][wv][1][0]);
            gload_lds16(xb1 + ws + 1024, &xs[(c + 1) & 1][wv][1][1024]);
        }
        const int delta = c * CHB - winstart(c);   // 0, except last chunk
        const char* xsw = &xs[c & 1][wv][0][0];

#pragma unroll
        for (int s = 0; s < CH; ++s) {
            const v4f* xr0 = (const v4f*)(xsw + delta + s * (F_IN * 4));
            const v4f* xr1 = (const v4f*)(xsw + WIN + delta + s * (F_IN * 4));
            v2f acc0 = {0.0f, 0.0f};               // (hA,hB) for b0
            v2f acc1 = {0.0f, 0.0f};               // (hA,hB) for b1
            // Two independent sequential-f chains (b0, b1); within each the
            // f-order is 0..39 ascending -> bit-exact vs reference.
#pragma unroll
            for (int q = 0; q < 10; ++q) {
                const v4f x0 = xr0[q];             // ds_read_b128 broadcast
                const v4f x1 = xr1[q];
                const v2f x0lo = x0.lo, x0hi = x0.hi;
                const v2f x1lo = x1.lo, x1hi = x1.hi;
                PKFMA_LO(acc0, x0lo, wab[4*q+0]);  // f=4q
                PKFMA_LO(acc1, x1lo, wab[4*q+0]);
                PKFMA_HI(acc0, x0lo, wab[4*q+1]);  // f=4q+1
                PKFMA_HI(acc1, x1lo, wab[4*q+1]);
                PKFMA_LO(acc0, x0hi, wab[4*q+2]);  // f=4q+2
                PKFMA_LO(acc1, x1hi, wab[4*q+2]);
                PKFMA_HI(acc0, x0hi, wab[4*q+3]);  // f=4q+3
                PKFMA_HI(acc1, x1hi, wab[4*q+3]);
            }
            // b0 update (exact validated op order)
            mA0 = __fsub_rn(__fadd_rn(__fmul_rn(0.9f, mA0), __fadd_rn(acc0.x, b1A)), rA0);
            mB0 = __fsub_rn(__fadd_rn(__fmul_rn(0.9f, mB0), __fadd_rn(acc0.y, b1B)), rB0);
            bool sA0 = mA0 > 1.0f, sB0 = mB0 > 1.0f;
            rA0 = sA0 ? 1.0f : 0.0f;
            rB0 = sB0 ? 1.0f : 0.0f;
            const unsigned long long lo0 = __ballot(sA0);
            const unsigned long long hi0 = __ballot(sB0);
            // b1 update
            mA1 = __fsub_rn(__fadd_rn(__fmul_rn(0.9f, mA1), __fadd_rn(acc1.x, b1A)), rA1);
            mB1 = __fsub_rn(__fadd_rn(__fmul_rn(0.9f, mB1), __fadd_rn(acc1.y, b1B)), rB1);
            bool sA1 = mA1 > 1.0f, sB1 = mB1 > 1.0f;
            rA1 = sA1 ? 1.0f : 0.0f;
            rB1 = sB1 ? 1.0f : 0.0f;
            const unsigned long long lo1 = __ballot(sA1);
            const unsigned long long hi1 = __ballot(sB1);
            if (li == 0) {
                mp[0] = make_ulonglong2(lo0, hi0); // masks[t][b0]
                mp[1] = make_ulonglong2(lo1, hi1); // masks[t][b1]
            }
            mp += B_TOTAL;
        }
        // prefetch must have landed before we read the other buffer
        asm volatile("s_waitcnt vmcnt(0)" ::: "memory");
    }
}

// ---------------------------------------------------------------------------
// Kernel B: cur2 sums, parallel over (t,b). Ascending-h individually-rounded
// adds of w2[c][h] over spiking h — identical numerics to the validated l2.
// ---------------------------------------------------------------------------
__global__ __launch_bounds__(256)
void snn_l2a(const ulonglong2* __restrict__ masks,
             const float* __restrict__ w2,
             float* __restrict__ cur2)
{
    __shared__ float w2s[H_DIM * C_OUT];   // [h][c] for bank spread
    const int tid = threadIdx.x;
    for (int i = tid; i < H_DIM * C_OUT; i += 256) {
        const int c = i / H_DIM, h = i % H_DIM;
        w2s[h * C_OUT + c] = w2[i];
    }
    __syncthreads();

    const size_t gid = (size_t)blockIdx.x * 256 + tid;   // == t*B_TOTAL + b
    const ulonglong2 mk = masks[gid];
    float s0 = 0.f, s1 = 0.f, s2 = 0.f, s3 = 0.f, s4 = 0.f;

    auto acc32 = [&](uint32_t w, int base) {
        while (w) {
            const int h = base + __builtin_ctz(w);
            w &= w - 1;
            const float* wp = &w2s[h * C_OUT];
            s0 = __fadd_rn(s0, wp[0]);
            s1 = __fadd_rn(s1, wp[1]);
            s2 = __fadd_rn(s2, wp[2]);
            s3 = __fadd_rn(s3, wp[3]);
            s4 = __fadd_rn(s4, wp[4]);
        }
    };
    acc32((uint32_t)(mk.x & 0xffffffffull), 0);
    acc32((uint32_t)(mk.x >> 32), 32);
    acc32((uint32_t)(mk.y & 0xffffffffull), 64);
    acc32((uint32_t)(mk.y >> 32), 96);

    float* o = cur2 + gid * C_OUT;
    o[0] = s0; o[1] = s1; o[2] = s2; o[3] = s3; o[4] = s4;
}

// ---------------------------------------------------------------------------
// Kernel C: layer-2 recurrence over t. Lane = (b,c), coalesced cur2/out,
// depth-4 static-unrolled prefetch. Ops identical to validated l2.
// ---------------------------------------------------------------------------
__global__ __launch_bounds__(256)
void snn_l2b(const float* __restrict__ cur2,
             const float* __restrict__ b2,
             float* __restrict__ out)
{
    const int gid = blockIdx.x * 256 + threadIdx.x;      // b*5 + c
    const float b2c = b2[gid % 5];
    const int STRIDE = B_TOTAL * C_OUT;                  // 40960
    float m2 = 0.0f, r2 = 0.0f;

    float f0 = cur2[0 * (size_t)STRIDE + gid];
    float f1 = cur2[1 * (size_t)STRIDE + gid];
    float f2 = cur2[2 * (size_t)STRIDE + gid];
    float f3 = cur2[3 * (size_t)STRIDE + gid];

#define L2B_STEP(F, TT)                                                        \
    {                                                                          \
        const float cur = __fadd_rn(F, b2c);                                   \
        m2 = __fsub_rn(__fadd_rn(__fmul_rn(0.9f, m2), cur), r2);               \
        const float s = (m2 > 1.0f) ? 1.0f : 0.0f;                             \
        r2 = s;                                                                \
        out[(size_t)(TT) * STRIDE + gid] = s;                                  \
        F = ((TT) + 4 < T_STEPS) ? cur2[(size_t)((TT) + 4) * STRIDE + gid]     \
                                 : 0.0f;                                       \
    }

    for (int t = 0; t < T_STEPS; t += 4) {
        L2B_STEP(f0, t + 0)
        L2B_STEP(f1, t + 1)
        L2B_STEP(f2, t + 2)
        L2B_STEP(f3, t + 3)
    }
#undef L2B_STEP
}

extern "C" void kernel_launch(void* const* d_in, const int* in_sizes, int n_in,
                              void* d_out, int out_size, void* d_ws, size_t ws_size,
                              hipStream_t stream) {
    const float* x  = (const float*)d_in[0];
    const float* w1 = (const float*)d_in[1];
    const float* b1 = (const float*)d_in[2];
    const float* w2 = (const float*)d_in[3];
    const float* b2 = (const float*)d_in[4];
    float* out = (float*)d_out;

    // ws layout: masks [t][b] 16B each = 26,214,400 B; cur2 [t][b][c] fp32 =
    // 32,768,000 B; total ~59 MB.
    ulonglong2* masks = (ulonglong2*)d_ws;
    float* cur2 = (float*)((char*)d_ws + (size_t)T_STEPS * B_TOTAL * 16);

    snn_l1 <<<dim3(B_TOTAL / 8),             dim3(256), 0, stream>>>(x, w1, b1, masks);
    snn_l2a<<<dim3(T_STEPS * B_TOTAL / 256), dim3(256), 0, stream>>>(masks, w2, cur2);
    snn_l2b<<<dim3(B_TOTAL * C_OUT / 256),   dim3(256), 0, stream>>>(cur2, b2, out);
}

// Round 18
// 293.459 us; speedup vs baseline: 1.7582x; 1.0024x over previous
//
#include <hip/hip_runtime.h>
#include <cstdint>

#define T_STEPS 200
#define B_TOTAL 8192
#define F_IN    40
#define H_DIM   128
#define C_OUT   5

#define CH      8                         // time steps per staged chunk
#define NCHUNK  (T_STEPS / CH)            // 25
#define CHB     (CH * F_IN * 4)           // 1280 bytes per chunk per b
#define WIN     2048                      // staged window bytes (2 x 1024)
#define ROWB    (T_STEPS * F_IN * 4)      // 32000 bytes per b

typedef float v2f __attribute__((ext_vector_type(2)));
typedef float v4f __attribute__((ext_vector_type(4)));

// v_pk_fma_f32: per-word IEEE fp32 FMA (bit-identical to v_fma_f32).
// op_sel broadcasts one word of the x-pair to both result words:
// LO -> word0 (x_f), HI -> word1 (x_{f+1}).  Validated bit-exact r6/r7/r17.
#define PKFMA_LO(acc, xp, wp)                                                  \
    asm("v_pk_fma_f32 %0, %1, %2, %0 op_sel:[0,0,0] op_sel_hi:[0,1,1]"        \
        : "+v"(acc) : "v"(xp), "v"(wp))
#define PKFMA_HI(acc, xp, wp)                                                  \
    asm("v_pk_fma_f32 %0, %1, %2, %0 op_sel:[1,0,0] op_sel_hi:[1,1,1]"        \
        : "+v"(acc) : "v"(xp), "v"(wp))

// async global->LDS, 16B per lane, dest = wave-uniform base + lane*16
__device__ __forceinline__ void gload_lds16(const void* g, void* l) {
    __builtin_amdgcn_global_load_lds(
        (const __attribute__((address_space(1))) void*)g,
        (__attribute__((address_space(3))) void*)l, 16, 0, 0);
}

// ---------------------------------------------------------------------------
// Kernel 0: pre-interleave w1 into the pk-FMA lane layout:
// wpairs[li*40 + f] = ( w1[li][f], w1[li+64][f] ).
// Kills the per-use repack (r17 post-mortem: ~1.8 excess VALU per pk-FMA =
// reload + 2 v_movs to build the VOP3P pair). A reload from wpairs is one
// global_load_dwordx2 at base + li*320 + f*8 (imm offset), zero VALU.
// ---------------------------------------------------------------------------
__global__ __launch_bounds__(256)
void prep_w(const float* __restrict__ w1, v2f* __restrict__ wpairs)
{
    const int i = blockIdx.x * 256 + threadIdx.x;     // [0, 64*40)
    if (i < 64 * F_IN) {
        const int li = i / F_IN, f = i % F_IN;
        v2f p;
        p.x = w1[li * F_IN + f];
        p.y = w1[(li + 64) * F_IN + f];
        wpairs[i] = p;
    }
}

// ---------------------------------------------------------------------------
// Kernel A: layer-1 recurrence. Exact fp32 numerics (validated r2/r5-r17):
// per-step sequential-f FMA chain (f = 0..39), +b1, then ((0.9*m)+cur)-reset,
// each op individually rounded. One wave per b; lane li owns h=li (acc.x)
// and h=li+64 (acc.y); two ballots give the 128-bit spike mask in
// ascending-h order. x staged 8 steps deep in per-wave-private LDS windows
// (no barriers). Structure = r7 PASS (best: 255us); weights now loaded from
// the pre-interleaved wpairs buffer (no repack).
// ---------------------------------------------------------------------------
__global__ __launch_bounds__(256, 4)
void snn_l1(const float* __restrict__ x,
            const v2f* __restrict__ wpairs,
            const float* __restrict__ b1,
            ulonglong2* __restrict__ masks)
{
    __shared__ __align__(16) char xs[2][4][WIN];   // 16 KiB

    const int li = threadIdx.x & 63;
    const int wv = threadIdx.x >> 6;
    const int b  = blockIdx.x * 4 + wv;
    const int hA = li, hB = li + 64;

    // weight pairs, already interleaved: wab[f] = (wA_f, wB_f)
    v2f wab[F_IN];
    {
        const v2f* wb = wpairs + li * F_IN;
#pragma unroll
        for (int f = 0; f < F_IN; ++f) wab[f] = wb[f];
    }
    const float b1A = b1[hA], b1B = b1[hB];
    float mA = 0.0f, mB = 0.0f, rA = 0.0f, rB = 0.0f;

    // per-lane global src: row base + lane*16
    const char* xb = (const char*)x + (size_t)b * ROWB + (size_t)li * 16;

    // window start in bytes for chunk c (last window shifted back, in-bounds)
    auto winstart = [](int c) { return (c == NCHUNK - 1) ? (ROWB - WIN) : c * CHB; };

    // stage chunk 0 into buffer 0
    gload_lds16(xb + winstart(0),        &xs[0][wv][0]);
    gload_lds16(xb + winstart(0) + 1024, &xs[0][wv][1024]);
    asm volatile("s_waitcnt vmcnt(0)" ::: "memory");

    ulonglong2* mp = masks + b;                    // strength-reduced store ptr

    for (int c = 0; c < NCHUNK; ++c) {
        // prefetch next chunk into the other buffer (issue early, wait late)
        if (c + 1 < NCHUNK) {
            const int ws = winstart(c + 1);
            gload_lds16(xb + ws,        &xs[(c + 1) & 1][wv][0]);
            gload_lds16(xb + ws + 1024, &xs[(c + 1) & 1][wv][1024]);
        }
        const int delta = c * CHB - winstart(c);   // 0, except last chunk
        const char* xsw = &xs[c & 1][wv][0];

#pragma unroll
        for (int sp = 0; sp < CH; sp += 2) {
            const v4f* xr0 = (const v4f*)(xsw + delta + (sp + 0) * (F_IN * 4));
            const v4f* xr1 = (const v4f*)(xsw + delta + (sp + 1) * (F_IN * 4));
            v2f acc0 = {0.0f, 0.0f};
            v2f acc1 = {0.0f, 0.0f};
            // Two independent sequential-f chains (steps sp, sp+1) in flight;
            // within each chain the f-order is 0..39 -> bit-exact.
#pragma unroll
            for (int q = 0; q < 10; ++q) {
                const v4f x0 = xr0[q];             // ds_read_b128 broadcast
                const v4f x1 = xr1[q];
                const v2f x0lo = x0.lo, x0hi = x0.hi;
                const v2f x1lo = x1.lo, x1hi = x1.hi;
                PKFMA_LO(acc0, x0lo, wab[4*q+0]);
                PKFMA_LO(acc1, x1lo, wab[4*q+0]);
                PKFMA_HI(acc0, x0lo, wab[4*q+1]);
                PKFMA_HI(acc1, x1lo, wab[4*q+1]);
                PKFMA_LO(acc0, x0hi, wab[4*q+2]);
                PKFMA_LO(acc1, x1hi, wab[4*q+2]);
                PKFMA_HI(acc0, x0hi, wab[4*q+3]);
                PKFMA_HI(acc1, x1hi, wab[4*q+3]);
            }
            // step sp
            mA = __fsub_rn(__fadd_rn(__fmul_rn(0.9f, mA), __fadd_rn(acc0.x, b1A)), rA);
            mB = __fsub_rn(__fadd_rn(__fmul_rn(0.9f, mB), __fadd_rn(acc0.y, b1B)), rB);
            bool sA = mA > 1.0f, sB = mB > 1.0f;
            rA = sA ? 1.0f : 0.0f;
            rB = sB ? 1.0f : 0.0f;
            unsigned long long lo = __ballot(sA);
            unsigned long long hi = __ballot(sB);
            if (li == 0) *mp = make_ulonglong2(lo, hi);
            mp += B_TOTAL;
            // step sp+1
            mA = __fsub_rn(__fadd_rn(__fmul_rn(0.9f, mA), __fadd_rn(acc1.x, b1A)), rA);
            mB = __fsub_rn(__fadd_rn(__fmul_rn(0.9f, mB), __fadd_rn(acc1.y, b1B)), rB);
            sA = mA > 1.0f; sB = mB > 1.0f;
            rA = sA ? 1.0f : 0.0f;
            rB = sB ? 1.0f : 0.0f;
            lo = __ballot(sA);
            hi = __ballot(sB);
            if (li == 0) *mp = make_ulonglong2(lo, hi);
            mp += B_TOTAL;
        }
        // prefetch must have landed before we read the other buffer
        asm volatile("s_waitcnt vmcnt(0)" ::: "memory");
    }
}

// ---------------------------------------------------------------------------
// Kernel B: cur2 sums, parallel over (t,b). Ascending-h individually-rounded
// adds of w2[c][h] over spiking h — identical numerics to the validated l2.
// ---------------------------------------------------------------------------
__global__ __launch_bounds__(256)
void snn_l2a(const ulonglong2* __restrict__ masks,
             const float* __restrict__ w2,
             float* __restrict__ cur2)
{
    __shared__ float w2s[H_DIM * C_OUT];   // [h][c] for bank spread
    const int tid = threadIdx.x;
    for (int i = tid; i < H_DIM * C_OUT; i += 256) {
        const int c = i / H_DIM, h = i % H_DIM;
        w2s[h * C_OUT + c] = w2[i];
    }
    __syncthreads();

    const size_t gid = (size_t)blockIdx.x * 256 + tid;   // == t*B_TOTAL + b
    const ulonglong2 mk = masks[gid];
    float s0 = 0.f, s1 = 0.f, s2 = 0.f, s3 = 0.f, s4 = 0.f;

    auto acc32 = [&](uint32_t w, int base) {
        while (w) {
            const int h = base + __builtin_ctz(w);
            w &= w - 1;
            const float* wp = &w2s[h * C_OUT];
            s0 = __fadd_rn(s0, wp[0]);
            s1 = __fadd_rn(s1, wp[1]);
            s2 = __fadd_rn(s2, wp[2]);
            s3 = __fadd_rn(s3, wp[3]);
            s4 = __fadd_rn(s4, wp[4]);
        }
    };
    acc32((uint32_t)(mk.x & 0xffffffffull), 0);
    acc32((uint32_t)(mk.x >> 32), 32);
    acc32((uint32_t)(mk.y & 0xffffffffull), 64);
    acc32((uint32_t)(mk.y >> 32), 96);

    float* o = cur2 + gid * C_OUT;
    o[0] = s0; o[1] = s1; o[2] = s2; o[3] = s3; o[4] = s4;
}

// ---------------------------------------------------------------------------
// Kernel C: layer-2 recurrence over t. Lane = (b,c), coalesced cur2/out,
// depth-4 static-unrolled prefetch. Ops identical to validated l2.
// ---------------------------------------------------------------------------
__global__ __launch_bounds__(256)
void snn_l2b(const float* __restrict__ cur2,
             const float* __restrict__ b2,
             float* __restrict__ out)
{
    const int gid = blockIdx.x * 256 + threadIdx.x;      // b*5 + c
    const float b2c = b2[gid % 5];
    const int STRIDE = B_TOTAL * C_OUT;                  // 40960
    float m2 = 0.0f, r2 = 0.0f;

    float f0 = cur2[0 * (size_t)STRIDE + gid];
    float f1 = cur2[1 * (size_t)STRIDE + gid];
    float f2 = cur2[2 * (size_t)STRIDE + gid];
    float f3 = cur2[3 * (size_t)STRIDE + gid];

#define L2B_STEP(F, TT)                                                        \
    {                                                                          \
        const float cur = __fadd_rn(F, b2c);                                   \
        m2 = __fsub_rn(__fadd_rn(__fmul_rn(0.9f, m2), cur), r2);               \
        const float s = (m2 > 1.0f) ? 1.0f : 0.0f;                             \
        r2 = s;                                                                \
        out[(size_t)(TT) * STRIDE + gid] = s;                                  \
        F = ((TT) + 4 < T_STEPS) ? cur2[(size_t)((TT) + 4) * STRIDE + gid]     \
                                 : 0.0f;                                       \
    }

    for (int t = 0; t < T_STEPS; t += 4) {
        L2B_STEP(f0, t + 0)
        L2B_STEP(f1, t + 1)
        L2B_STEP(f2, t + 2)
        L2B_STEP(f3, t + 3)
    }
#undef L2B_STEP
}

extern "C" void kernel_launch(void* const* d_in, const int* in_sizes, int n_in,
                              void* d_out, int out_size, void* d_ws, size_t ws_size,
                              hipStream_t stream) {
    const float* x  = (const float*)d_in[0];
    const float* w1 = (const float*)d_in[1];
    const float* b1 = (const float*)d_in[2];
    const float* w2 = (const float*)d_in[3];
    const float* b2 = (const float*)d_in[4];
    float* out = (float*)d_out;

    // ws layout: masks [t][b] 16B = 26,214,400 B; cur2 [t][b][c] fp32 =
    // 32,768,000 B; wpairs 64*40*8 = 20,480 B.  Total ~59 MB.
    ulonglong2* masks = (ulonglong2*)d_ws;
    float* cur2 = (float*)((char*)d_ws + (size_t)T_STEPS * B_TOTAL * 16);
    v2f* wpairs = (v2f*)((char*)d_ws + (size_t)T_STEPS * B_TOTAL * 16
                                     + (size_t)T_STEPS * B_TOTAL * C_OUT * 4);

    prep_w <<<dim3(10),                      dim3(256), 0, stream>>>(w1, wpairs);
    snn_l1 <<<dim3(B_TOTAL / 4),             dim3(256), 0, stream>>>(x, wpairs, b1, masks);
    snn_l2a<<<dim3(T_STEPS * B_TOTAL / 256), dim3(256), 0, stream>>>(masks, w2, cur2);
    snn_l2b<<<dim3(B_TOTAL * C_OUT / 256),   dim3(256), 0, stream>>>(cur2, b2, out);
}